// Round 3
// baseline (398.592 us; speedup 1.0000x reference)
//
#include <hip/hip_runtime.h>

#define A_N 100000
#define B_N 8
#define C_N 80
#define M_N 32

typedef float vfloat4 __attribute__((ext_vector_type(4)));  // clang-native: OK for nontemporal builtin

// Workspace layout (floats): [0:8) cls_sum, [8:16) reg_sum, [16:24) npos (as int)

// Background focal term for 4 classes: returns sum_j p_j^2 * log(1-p_j).
// Caller multiplies by -0.75 (alpha complement) or 0 (ignored anchor).
__device__ __forceinline__ float bg_s4(vfloat4 v) {
    float p0 = fminf(fmaxf(v.x, 1e-4f), 1.0f - 1e-4f);
    float p1 = fminf(fmaxf(v.y, 1e-4f), 1.0f - 1e-4f);
    float p2 = fminf(fmaxf(v.z, 1e-4f), 1.0f - 1e-4f);
    float p3 = fminf(fmaxf(v.w, 1e-4f), 1.0f - 1e-4f);
    float l0 = __logf(1.0f - p0);
    float l1 = __logf(1.0f - p1);
    float l2 = __logf(1.0f - p2);
    float l3 = __logf(1.0f - p3);
    return fmaf(p0 * p0, l0, fmaf(p1 * p1, l1, fmaf(p2 * p2, l2, p3 * p3 * l3)));
}

__global__ __launch_bounds__(256) void focal_main(
    const vfloat4* __restrict__ cls4,  // [B, A, 20] as float4 (C=80 floats/anchor)
    const float*  __restrict__ clsf,   // same buffer, scalar view (rare one-hot reads)
    const float4* __restrict__ reg4,   // [B, A] float4
    const float4* __restrict__ anc4,   // [A] float4
    const float*  __restrict__ ann,    // [B, 32, 9]
    float* __restrict__ cls_sum, float* __restrict__ reg_sum, int* __restrict__ npos)
{
    __shared__ float annL[M_N][6];   // x0,y0,x1,y1,label,area
    __shared__ float scaleL[256];    // -0.75 (not ignored) or 0.0 (ignored/invalid)
    __shared__ float redA[4];
    __shared__ float redB[4];
    __shared__ int   redI[4];

    const int b   = blockIdx.y;
    const int a0  = blockIdx.x * 256;
    const int tid = threadIdx.x;

    // --- load annotations for this image into LDS ---
    for (int i = tid; i < M_N * 5; i += 256) {
        int m = i / 5, c = i % 5;
        annL[m][c] = ann[(b * M_N + m) * 9 + c];
    }
    __syncthreads();
    if (tid < M_N) {
        annL[tid][5] = (annL[tid][2] - annL[tid][0]) * (annL[tid][3] - annL[tid][1]);
    }
    __syncthreads();

    const int a = a0 + tid;
    const bool valid = a < A_N;
    const int nA = min(256, A_N - a0);
    const bool full = (nA == 256);
    const vfloat4* cbase = cls4 + ((size_t)b * A_N + a0) * 20;

    // --- 1) anchor load FIRST (oldest outstanding vmem -> its wait doesn't drain the batch) ---
    float4 an = anc4[valid ? a : A_N - 1];

    // --- 2) issue the entire cls tile (20 nontemporal loads) before any compute ---
    vfloat4 bufA[10], bufB[10];
    if (full) {
        #pragma unroll
        for (int u = 0; u < 10; ++u)
            bufA[u] = __builtin_nontemporal_load(cbase + tid + (u << 8));
        #pragma unroll
        for (int u = 0; u < 10; ++u)
            bufB[u] = __builtin_nontemporal_load(cbase + tid + ((u + 10) << 8));
    }

    // --- 3) Phase A: IoU assignment, fully overlapped with in-flight cls loads ---
    float aw = an.z - an.x, ah = an.w - an.y;
    float aArea = aw * ah;
    float best = -1.0f; int bidx = 0;
    #pragma unroll 8
    for (int m = 0; m < M_N; ++m) {
        float iw = fminf(an.z, annL[m][2]) - fmaxf(an.x, annL[m][0]);
        float ih = fminf(an.w, annL[m][3]) - fmaxf(an.y, annL[m][1]);
        iw = fmaxf(iw, 0.0f); ih = fmaxf(ih, 0.0f);
        float inter = iw * ih;
        float ua = fmaxf(aArea + annL[m][5] - inter, 1e-8f);
        float iou = inter / ua;
        if (iou > best) { best = iou; bidx = m; }   // strict > == first-max (JAX argmax)
    }
    const bool pos = valid && (best >= 0.5f);
    const int  st  = valid ? (pos ? 2 : (best < 0.4f ? 0 : 1)) : 1;
    scaleL[tid] = (st != 1) ? -0.75f : 0.0f;
    __syncthreads();   // publish scaleL (barrier drains vmem, but Phase A already ran under load latency)

    // --- 4) consume: pure background sweep, zero data-dependent control flow ---
    float clsacc = 0.0f;
    if (full) {
        #pragma unroll
        for (int u = 0; u < 10; ++u) {
            int i = tid + (u << 8);
            clsacc = fmaf(scaleL[i / 20], bg_s4(bufA[u]), clsacc);
        }
        #pragma unroll
        for (int u = 0; u < 10; ++u) {
            int i = tid + ((u + 10) << 8);
            clsacc = fmaf(scaleL[i / 20], bg_s4(bufB[u]), clsacc);
        }
    } else {
        const int n4 = nA * 20;
        for (int i = tid; i < n4; i += 256) {
            vfloat4 v = __builtin_nontemporal_load(cbase + i);
            clsacc = fmaf(scaleL[i / 20], bg_s4(v), clsacc);
        }
    }

    // --- 5) positive-anchor work LAST (divergent loads no longer stall the stream) ---
    float regacc = 0.0f;
    const unsigned long long bal = __ballot(pos);
    if (bal) {                 // wave-uniform skip for all-negative waves
        if (pos) {
            float4 r = reg4[(size_t)b * A_N + a];
            float gx0 = annL[bidx][0], gy0 = annL[bidx][1];
            float gx1 = annL[bidx][2], gy1 = annL[bidx][3];
            float gwr = gx1 - gx0, ghr = gy1 - gy0;
            float gcx = gx0 + 0.5f * gwr, gcy = gy0 + 0.5f * ghr;
            float gw = fmaxf(gwr, 1.0f), gh = fmaxf(ghr, 1.0f);
            float acx = an.x + 0.5f * aw, acy = an.y + 0.5f * ah;
            float t0 = (gcx - acx) / aw * 10.0f;
            float t1 = (gcy - acy) / ah * 10.0f;
            float t2 = __logf(gw / aw) * 5.0f;
            float t3 = __logf(gh / ah) * 5.0f;
            float d0 = fabsf(t0 - r.x), d1 = fabsf(t1 - r.y);
            float d2 = fabsf(t2 - r.z), d3 = fabsf(t3 - r.w);
            const float th = 1.0f / 9.0f;
            const float hs = 0.5f / 9.0f;
            regacc  = (d0 <= th) ? 4.5f * d0 * d0 : d0 - hs;
            regacc += (d1 <= th) ? 4.5f * d1 * d1 : d1 - hs;
            regacc += (d2 <= th) ? 4.5f * d2 * d2 : d2 - hs;
            regacc += (d3 <= th) ? 4.5f * d3 * d3 : d3 - hs;

            // one-hot correction: true term minus the background term already accumulated
            int ci = (int)annL[bidx][4];
            float pc = clsf[((size_t)b * A_N + a) * C_N + ci];
            pc = fminf(fmaxf(pc, 1e-4f), 1.0f - 1e-4f);
            float qc = 1.0f - pc;
            clsacc += -0.25f * qc * qc * __logf(pc) + 0.75f * pc * pc * __logf(qc);
        }
    }

    // --- 6) single merged reduction: reg + cls + npos ---
    #pragma unroll
    for (int o = 32; o > 0; o >>= 1) {
        regacc += __shfl_down(regacc, o, 64);
        clsacc += __shfl_down(clsacc, o, 64);
    }
    const int lane = tid & 63, wid = tid >> 6;
    if (lane == 0) { redA[wid] = regacc; redB[wid] = clsacc; redI[wid] = __popcll(bal); }
    __syncthreads();
    if (tid == 0) {
        float rs = redA[0] + redA[1] + redA[2] + redA[3];
        float cs = redB[0] + redB[1] + redB[2] + redB[3];
        int   np = redI[0] + redI[1] + redI[2] + redI[3];
        if (rs != 0.0f) atomicAdd(&reg_sum[b], rs);
        if (np)         atomicAdd(&npos[b], np);
        atomicAdd(&cls_sum[b], cs);
    }
}

__global__ void focal_finalize(const float* __restrict__ cls_sum,
                               const float* __restrict__ reg_sum,
                               const int* __restrict__ npos,
                               float* __restrict__ out)
{
    if (threadIdx.x == 0) {
        float c = 0.0f, r = 0.0f;
        for (int b = 0; b < B_N; ++b) {
            float np = (float)npos[b];
            c += cls_sum[b] / fmaxf(np, 1.0f);
            r += (npos[b] > 0) ? reg_sum[b] / (4.0f * np) : 0.0f;
        }
        out[0] = c / (float)B_N;
        out[1] = r / (float)B_N;
    }
}

extern "C" void kernel_launch(void* const* d_in, const int* in_sizes, int n_in,
                              void* d_out, int out_size, void* d_ws, size_t ws_size,
                              hipStream_t stream) {
    const float* cls = (const float*)d_in[0];   // [B, A, C]
    const float* reg = (const float*)d_in[1];   // [B, A, 4]
    const float* anc = (const float*)d_in[2];   // [1, A, 4]
    const float* ann = (const float*)d_in[3];   // [B, M, 9]

    float* ws      = (float*)d_ws;
    float* cls_sum = ws;
    float* reg_sum = ws + 8;
    int*   npos    = (int*)(ws + 16);

    (void)hipMemsetAsync(d_ws, 0, 24 * sizeof(float), stream);

    dim3 grid((A_N + 255) / 256, B_N);
    focal_main<<<grid, 256, 0, stream>>>(
        (const vfloat4*)cls, cls, (const float4*)reg, (const float4*)anc, ann,
        cls_sum, reg_sum, npos);

    focal_finalize<<<1, 64, 0, stream>>>(cls_sum, reg_sum, npos, (float*)d_out);
}

// Round 4
// 375.389 us; speedup vs baseline: 1.0618x; 1.0618x over previous
//
#include <hip/hip_runtime.h>

#define A_N 100000
#define B_N 8
#define C_N 80
#define M_N 32

typedef float vfloat4 __attribute__((ext_vector_type(4)));  // clang-native: OK for nontemporal builtin

// Workspace layout (floats): [0:8) cls_sum, [8:16) reg_sum, [16:24) npos (as int)

// Background focal term for 4 classes: returns sum_j p_j^2 * log(1-p_j).
// Caller multiplies by -0.75 (alpha complement) or 0 (ignored anchor).
__device__ __forceinline__ float bg_s4(vfloat4 v) {
    float p0 = fminf(fmaxf(v.x, 1e-4f), 1.0f - 1e-4f);
    float p1 = fminf(fmaxf(v.y, 1e-4f), 1.0f - 1e-4f);
    float p2 = fminf(fmaxf(v.z, 1e-4f), 1.0f - 1e-4f);
    float p3 = fminf(fmaxf(v.w, 1e-4f), 1.0f - 1e-4f);
    float l0 = __logf(1.0f - p0);
    float l1 = __logf(1.0f - p1);
    float l2 = __logf(1.0f - p2);
    float l3 = __logf(1.0f - p3);
    return fmaf(p0 * p0, l0, fmaf(p1 * p1, l1, fmaf(p2 * p2, l2, p3 * p3 * l3)));
}

__global__ __launch_bounds__(256) void focal_main(
    const vfloat4* __restrict__ cls4,  // [B, A, 20] as float4 (C=80 floats/anchor)
    const float*  __restrict__ clsf,   // same buffer, scalar view (rare one-hot reads)
    const float4* __restrict__ reg4,   // [B, A] float4
    const float4* __restrict__ anc4,   // [A] float4
    const float*  __restrict__ ann,    // [B, 32, 9]
    float* __restrict__ cls_sum, float* __restrict__ reg_sum, int* __restrict__ npos)
{
    __shared__ float annL[M_N][6];   // x0,y0,x1,y1,label,area
    __shared__ float redA[4];
    __shared__ float redB[4];
    __shared__ int   redI[4];

    const int b    = blockIdx.y;
    const int a0   = blockIdx.x * 256;
    const int tid  = threadIdx.x;
    const int lane = tid & 63;
    const int wid  = tid >> 6;

    // --- annotations -> LDS (single barrier; area fused into the same pass) ---
    if (tid < M_N) {
        const float* ar = ann + ((size_t)b * M_N + tid) * 9;
        float x0 = ar[0], y0 = ar[1], x1 = ar[2], y1 = ar[3], lb = ar[4];
        annL[tid][0] = x0; annL[tid][1] = y0;
        annL[tid][2] = x1; annL[tid][3] = y1;
        annL[tid][4] = lb; annL[tid][5] = (x1 - x0) * (y1 - y0);
    }
    __syncthreads();   // the ONLY barrier before the end-of-block reduction

    // --- wave-private anchor range: wave owns 64 anchors AND their cls slab ---
    const int aw0   = a0 + (wid << 6);
    const int a     = aw0 + lane;
    const bool valid = a < A_N;
    const int vA    = min(64, A_N - aw0);   // valid anchors in this wave (can be <=0)

    float4 an = anc4[valid ? a : (A_N - 1)];

    // --- IoU assignment (lane = anchor) ---
    float aw = an.z - an.x, ah = an.w - an.y;
    float aArea = aw * ah;
    float best = -1.0f; int bidx = 0;
    #pragma unroll 8
    for (int m = 0; m < M_N; ++m) {
        float iw = fminf(an.z, annL[m][2]) - fmaxf(an.x, annL[m][0]);
        float ih = fminf(an.w, annL[m][3]) - fmaxf(an.y, annL[m][1]);
        iw = fmaxf(iw, 0.0f); ih = fmaxf(ih, 0.0f);
        float inter = iw * ih;
        float ua = fmaxf(aArea + annL[m][5] - inter, 1e-8f);
        float iou = inter / ua;
        if (iou > best) { best = iou; bidx = m; }   // strict > == first-max (JAX argmax)
    }
    const bool pos = valid && (best >= 0.5f);
    const int  st  = valid ? (pos ? 2 : (best < 0.4f ? 0 : 1)) : 1;
    const float myscale = (st != 1) ? -0.75f : 0.0f;

    // --- rare positive work (reg loss + one-hot cls correction), wave-uniform skip ---
    float regacc = 0.0f;
    float clsacc = 0.0f;
    const unsigned long long bal = __ballot(pos);
    if (bal) {
        if (pos) {
            float4 r = reg4[(size_t)b * A_N + a];
            float gx0 = annL[bidx][0], gy0 = annL[bidx][1];
            float gx1 = annL[bidx][2], gy1 = annL[bidx][3];
            float gwr = gx1 - gx0, ghr = gy1 - gy0;
            float gcx = gx0 + 0.5f * gwr, gcy = gy0 + 0.5f * ghr;
            float gw = fmaxf(gwr, 1.0f), gh = fmaxf(ghr, 1.0f);
            float acx = an.x + 0.5f * aw, acy = an.y + 0.5f * ah;
            float t0 = (gcx - acx) / aw * 10.0f;
            float t1 = (gcy - acy) / ah * 10.0f;
            float t2 = __logf(gw / aw) * 5.0f;
            float t3 = __logf(gh / ah) * 5.0f;
            float d0 = fabsf(t0 - r.x), d1 = fabsf(t1 - r.y);
            float d2 = fabsf(t2 - r.z), d3 = fabsf(t3 - r.w);
            const float th = 1.0f / 9.0f;
            const float hs = 0.5f / 9.0f;
            regacc  = (d0 <= th) ? 4.5f * d0 * d0 : d0 - hs;
            regacc += (d1 <= th) ? 4.5f * d1 * d1 : d1 - hs;
            regacc += (d2 <= th) ? 4.5f * d2 * d2 : d2 - hs;
            regacc += (d3 <= th) ? 4.5f * d3 * d3 : d3 - hs;

            // one-hot correction: true term minus the background term phase B will add
            int ci = (int)annL[bidx][4];
            float pc = clsf[((size_t)b * A_N + a) * C_N + ci];
            pc = fminf(fmaxf(pc, 1e-4f), 1.0f - 1e-4f);
            float qc = 1.0f - pc;
            clsacc = -0.25f * qc * qc * __logf(pc) + 0.75f * pc * pc * __logf(qc);
        }
    }

    // --- streaming background sweep: NO barrier between load issue and consume ---
    // Wave reads its contiguous 64-anchor slab (1280 float4, 1 KB/instr coalesced).
    // scale gather is an in-wave shfl (ds_bpermute) -> counted vmcnt waits, pipe never drains.
    if (vA >= 64) {
        const vfloat4* wbase = cls4 + ((size_t)b * A_N + aw0) * 20;

        vfloat4 bufA[10], bufB[10];
        #pragma unroll
        for (int u = 0; u < 10; ++u)
            bufA[u] = __builtin_nontemporal_load(wbase + (u << 6) + lane);

        // scale for stream step u: anchor ((u<<6)+lane)/20 — in-wave gather,
        // computed while the first batch of loads is in flight
        float sc[20];
        #pragma unroll
        for (int u = 0; u < 20; ++u)
            sc[u] = __shfl(myscale, ((u << 6) + lane) / 20, 64);

        #pragma unroll
        for (int u = 0; u < 10; ++u) {
            bufB[u] = __builtin_nontemporal_load(wbase + ((u + 10) << 6) + lane);
            clsacc = fmaf(sc[u], bg_s4(bufA[u]), clsacc);   // waits vmcnt(counted), ~10 stay in flight
        }
        #pragma unroll
        for (int u = 0; u < 10; ++u)
            clsacc = fmaf(sc[u + 10], bg_s4(bufB[u]), clsacc);
    } else if (vA > 0) {
        const vfloat4* wbase = cls4 + ((size_t)b * A_N + aw0) * 20;
        const int n4 = vA * 20;
        for (int i = lane; i < n4; i += 64) {
            float s = __shfl(myscale, i / 20, 64);
            clsacc = fmaf(s, bg_s4(__builtin_nontemporal_load(wbase + i)), clsacc);
        }
    }

    // --- merged block reduction: reg + cls + npos ---
    #pragma unroll
    for (int o = 32; o > 0; o >>= 1) {
        regacc += __shfl_down(regacc, o, 64);
        clsacc += __shfl_down(clsacc, o, 64);
    }
    if (lane == 0) { redA[wid] = regacc; redB[wid] = clsacc; redI[wid] = __popcll(bal); }
    __syncthreads();
    if (tid == 0) {
        float rs = redA[0] + redA[1] + redA[2] + redA[3];
        float cs = redB[0] + redB[1] + redB[2] + redB[3];
        int   np = redI[0] + redI[1] + redI[2] + redI[3];
        if (rs != 0.0f) atomicAdd(&reg_sum[b], rs);
        if (np)         atomicAdd(&npos[b], np);
        atomicAdd(&cls_sum[b], cs);
    }
}

__global__ void focal_finalize(const float* __restrict__ cls_sum,
                               const float* __restrict__ reg_sum,
                               const int* __restrict__ npos,
                               float* __restrict__ out)
{
    if (threadIdx.x == 0) {
        float c = 0.0f, r = 0.0f;
        for (int b = 0; b < B_N; ++b) {
            float np = (float)npos[b];
            c += cls_sum[b] / fmaxf(np, 1.0f);
            r += (npos[b] > 0) ? reg_sum[b] / (4.0f * np) : 0.0f;
        }
        out[0] = c / (float)B_N;
        out[1] = r / (float)B_N;
    }
}

extern "C" void kernel_launch(void* const* d_in, const int* in_sizes, int n_in,
                              void* d_out, int out_size, void* d_ws, size_t ws_size,
                              hipStream_t stream) {
    const float* cls = (const float*)d_in[0];   // [B, A, C]
    const float* reg = (const float*)d_in[1];   // [B, A, 4]
    const float* anc = (const float*)d_in[2];   // [1, A, 4]
    const float* ann = (const float*)d_in[3];   // [B, M, 9]

    float* ws      = (float*)d_ws;
    float* cls_sum = ws;
    float* reg_sum = ws + 8;
    int*   npos    = (int*)(ws + 16);

    (void)hipMemsetAsync(d_ws, 0, 24 * sizeof(float), stream);

    dim3 grid((A_N + 255) / 256, B_N);
    focal_main<<<grid, 256, 0, stream>>>(
        (const vfloat4*)cls, cls, (const float4*)reg, (const float4*)anc, ann,
        cls_sum, reg_sum, npos);

    focal_finalize<<<1, 64, 0, stream>>>(cls_sum, reg_sum, npos, (float*)d_out);
}